// Round 2
// baseline (212.017 us; speedup 1.0000x reference)
//
#include <hip/hip_runtime.h>

// Problem constants (n=4, L=8192, h=8, e=64, fp32)
#define N_      4
#define L_      8192
#define H_      8
#define E_      64
#define NH_     (N_ * H_)          // 32
#define STRIDE_ (H_ * E_)          // 512 floats between consecutive s/l rows
#define SPLIT_  32                 // s-split for phase 1 (keeps atomics at 4.2M)
#define CHUNK_  (L_ / SPLIT_)      // 256 rows per block
#define TS_     16                 // rows per staged tile
#define NT_     (CHUNK_ / TS_)     // 16 tiles

#define WS_KV_FLOATS    ((size_t)NH_ * E_ * E_)
#define WS_TOTAL_FLOATS (WS_KV_FLOATS + (size_t)NH_ * E_)

__device__ __forceinline__ float featmap(float x) {
    float xs = x * 0.35355339059327373f;     // * 64^-0.25
    return xs > 0.0f ? xs + 1.0f : __expf(xs);
}
__device__ __forceinline__ float4 featmap4(float4 k) {
    k.x = featmap(k.x); k.y = featmap(k.y);
    k.z = featmap(k.z); k.w = featmap(k.w);
    return k;
}

// ---------------------------------------------------------------------------
// Phase 1: KV[d][m] += sum_s kf[s,d]*v[s,m], ksum[d] += sum_s kf[s,d].
// 128 threads (2 waves). Thread grid 16(d-groups)x8(m-groups), 4x8 tile each
// -> full 64x64 output per block, no cross-wave reduction.
// Double-buffered LDS + register prefetch, ONE barrier per tile.
// ---------------------------------------------------------------------------
__global__ __launch_bounds__(128, 2) void la_phase1(
    const float* __restrict__ keys, const float* __restrict__ values,
    float* __restrict__ ws)
{
    const int blk   = blockIdx.x;
    const int nh    = blk / SPLIT_;
    const int chunk = blk % SPLIT_;
    const int n = nh / H_, h = nh % H_;
    const int tid = threadIdx.x;

    const int d16 = tid >> 3;    // 0..15 : d-group (4 d each)
    const int m8  = tid & 7;     // 0..7  : m-group (8 m each)
    const int row = tid >> 4;    // 0..7  : staging row (half-tile)
    const int col = tid & 15;    // 0..15 : staging float4 col

    __shared__ float kt[2][TS_][E_];
    __shared__ float vt[2][TS_][E_];

    float acc[4][8];
    #pragma unroll
    for (int i = 0; i < 4; ++i)
        #pragma unroll
        for (int j = 0; j < 8; ++j) acc[i][j] = 0.f;
    float ks[4] = {0.f, 0.f, 0.f, 0.f};

    const size_t base = ((size_t)n * L_ * H_ + h) * E_;
    const int s0 = chunk * CHUNK_;

    // Prologue: load tile 0 into registers.
    float4 kr0, kr1, vr0, vr1, nk0, nk1, nv0, nv1;
    {
        const size_t r0 = base + (size_t)(s0 + row) * STRIDE_ + col * 4;
        const size_t r1 = base + (size_t)(s0 + row + 8) * STRIDE_ + col * 4;
        kr0 = *reinterpret_cast<const float4*>(keys + r0);
        kr1 = *reinterpret_cast<const float4*>(keys + r1);
        vr0 = *reinterpret_cast<const float4*>(values + r0);
        vr1 = *reinterpret_cast<const float4*>(values + r1);
    }
    nk0 = nk1 = nv0 = nv1 = make_float4(0.f, 0.f, 0.f, 0.f);

    for (int t = 0; t < NT_; ++t) {
        const int buf = t & 1;
        // featmap current k tile, accumulate ksum partials (both f4 share col)
        float4 kw0 = featmap4(kr0), kw1 = featmap4(kr1);
        ks[0] += kw0.x + kw1.x; ks[1] += kw0.y + kw1.y;
        ks[2] += kw0.z + kw1.z; ks[3] += kw0.w + kw1.w;

        *reinterpret_cast<float4*>(&kt[buf][row    ][col * 4]) = kw0;
        *reinterpret_cast<float4*>(&kt[buf][row + 8][col * 4]) = kw1;
        *reinterpret_cast<float4*>(&vt[buf][row    ][col * 4]) = vr0;
        *reinterpret_cast<float4*>(&vt[buf][row + 8][col * 4]) = vr1;

        // Issue next-tile loads (vmcnt wait lands at next iter's featmap)
        if (t + 1 < NT_) {
            const int s1 = s0 + (t + 1) * TS_;
            const size_t r0 = base + (size_t)(s1 + row) * STRIDE_ + col * 4;
            const size_t r1 = base + (size_t)(s1 + row + 8) * STRIDE_ + col * 4;
            nk0 = *reinterpret_cast<const float4*>(keys + r0);
            nk1 = *reinterpret_cast<const float4*>(keys + r1);
            nv0 = *reinterpret_cast<const float4*>(values + r0);
            nv1 = *reinterpret_cast<const float4*>(values + r1);
        }

        __syncthreads();   // tile visible; also gates next iter's buffer write

        const float (*ktb)[E_] = kt[buf];
        const float (*vtb)[E_] = vt[buf];
        #pragma unroll
        for (int s = 0; s < TS_; ++s) {
            float4 kk  = *reinterpret_cast<const float4*>(&ktb[s][d16 * 4]);
            float4 vv0 = *reinterpret_cast<const float4*>(&vtb[s][m8 * 8]);
            float4 vv1 = *reinterpret_cast<const float4*>(&vtb[s][m8 * 8 + 4]);
            float ka[4] = {kk.x, kk.y, kk.z, kk.w};
            float va[8] = {vv0.x, vv0.y, vv0.z, vv0.w,
                           vv1.x, vv1.y, vv1.z, vv1.w};
            #pragma unroll
            for (int i = 0; i < 4; ++i)
                #pragma unroll
                for (int j = 0; j < 8; ++j)
                    acc[i][j] = fmaf(ka[i], va[j], acc[i][j]);
        }
        kr0 = nk0; kr1 = nk1; vr0 = nv0; vr1 = nv1;
    }

    // KV partial accumulation
    float* W = ws + (size_t)nh * (E_ * E_);
    #pragma unroll
    for (int i = 0; i < 4; ++i)
        #pragma unroll
        for (int j = 0; j < 8; ++j)
            atomicAdd(&W[(d16 * 4 + i) * E_ + (m8 * 8 + j)], acc[i][j]);

    // ksum: per-thread f4 partials -> LDS scratch -> 64-thread reduce -> atomic
    __syncthreads();
    float* ksb = &kt[0][0][0];               // reuse: [128][4] scratch (2 KB)
    *reinterpret_cast<float4*>(&ksb[tid * 4]) =
        make_float4(ks[0], ks[1], ks[2], ks[3]);
    __syncthreads();
    if (tid < E_) {
        const int c = tid >> 2, j = tid & 3;
        float s = 0.f;
        #pragma unroll
        for (int r = 0; r < 8; ++r) s += ksb[(r * 16 + c) * 4 + j];
        atomicAdd(&ws[WS_KV_FLOATS + (size_t)nh * E_ + tid], s);
    }
}

// ---------------------------------------------------------------------------
// Phase 2: out[l][m] = z * sum_d qf[d] * W[d][m]. lane = m; KV column in VGPRs.
// Register prefetch of next row's q hides the per-row 256 B load latency.
// ---------------------------------------------------------------------------
__global__ __launch_bounds__(256) void la_phase2(
    const float* __restrict__ queries, const float* __restrict__ ws,
    float* __restrict__ out)
{
    const int blk  = blockIdx.x;
    const int nh   = blk >> 6;        // 64 blocks per (n,h)
    const int tile = blk & 63;
    const int n = nh / H_, h = nh % H_;
    const int t = threadIdx.x;
    const int w = t >> 6, lane = t & 63;

    const float* W = ws + (size_t)nh * (E_ * E_);
    float kv[E_];
    #pragma unroll
    for (int d = 0; d < E_; ++d) kv[d] = W[d * E_ + lane];
    const float ksum_l = ws[WS_KV_FLOATS + (size_t)nh * E_ + lane];

    __shared__ float qbuf[4][E_];

    const size_t base = ((size_t)n * L_ * H_ + h) * E_;
    const int row0 = tile * 128 + w * 32;

    size_t off = base + (size_t)row0 * STRIDE_ + lane;
    float q_raw = queries[off];

    for (int r = 0; r < 32; ++r) {
        const size_t off_cur = off;
        float q_next = 0.f;
        if (r < 31) {                      // prefetch next row
            off += STRIDE_;
            q_next = queries[off];
        }
        const float qf = featmap(q_raw);

        // z = 1 / (sum_d qf[d]*ksum[d] + eps)
        float zp = qf * ksum_l;
        #pragma unroll
        for (int sh = 32; sh >= 1; sh >>= 1) zp += __shfl_xor(zp, sh);
        const float z = 1.0f / (zp + 1e-6f);

        qbuf[w][lane] = qf;
        __builtin_amdgcn_wave_barrier();

        float acc = 0.f;
        #pragma unroll
        for (int d0 = 0; d0 < E_; d0 += 4) {
            float4 q4 = *reinterpret_cast<const float4*>(&qbuf[w][d0]);
            acc = fmaf(q4.x, kv[d0 + 0], acc);
            acc = fmaf(q4.y, kv[d0 + 1], acc);
            acc = fmaf(q4.z, kv[d0 + 2], acc);
            acc = fmaf(q4.w, kv[d0 + 3], acc);
        }
        __builtin_amdgcn_wave_barrier();

        out[off_cur] = acc * z;
        q_raw = q_next;
    }
}

extern "C" void kernel_launch(void* const* d_in, const int* in_sizes, int n_in,
                              void* d_out, int out_size, void* d_ws, size_t ws_size,
                              hipStream_t stream) {
    (void)in_sizes; (void)n_in; (void)out_size; (void)ws_size;
    const float* q = (const float*)d_in[0];
    const float* k = (const float*)d_in[1];
    const float* v = (const float*)d_in[2];
    float* outp = (float*)d_out;
    float* ws   = (float*)d_ws;

    hipMemsetAsync(d_ws, 0, WS_TOTAL_FLOATS * sizeof(float), stream);
    la_phase1<<<NH_ * SPLIT_, 128, 0, stream>>>(k, v, ws);
    la_phase2<<<NH_ * 64, 256, 0, stream>>>(q, ws, outp);
}